// Round 1
// baseline (342.785 us; speedup 1.0000x reference)
//
#include <hip/hip_runtime.h>

// ---------------- constants ----------------
__device__ __constant__ int GRADE_C[16] = {0,1,1,1,1,2,2,2,2,2,2,3,3,3,3,4};
__device__ __constant__ int INNER_C[8]  = {0,2,3,4,8,9,10,14};

// workspace layout (float indices)
#define OFF_QFT 0          // qfT[n][d(64)][h(8)]  : 1024*512
#define OFF_KF  524288     // kf[n][64]            : 1024*64
#define OFF_VC  589824     // Vc[n][96] (mv64+s32) : 1024*96
#define OFF_GW  688128     // gw[c(128)][h(8)]
#define OFF_GH  689152     // Gh[8] then Ch[8]
#define SB_BYTE 3145728    // bf16 s[q][k][h] : 1024*1024*8*2 = 16 MB

static __device__ __forceinline__ unsigned short f2bf(float f) {
    unsigned int u = __float_as_uint(f);
    u = u + 0x7fffu + ((u >> 16) & 1u);
    return (unsigned short)(u >> 16);
}
static __device__ __forceinline__ float bf2f(unsigned int b) {
    return __uint_as_float(b << 16);
}

// ---------------- kernel P: projections ----------------
__global__ __launch_bounds__(256) void kproj(
    const float* __restrict__ mv, const float* __restrict__ s,
    const float* __restrict__ q_w_mv, const float* __restrict__ q_w_s,
    const float* __restrict__ k_w_mv, const float* __restrict__ k_w_s,
    const float* __restrict__ v_w_mv, const float* __restrict__ v_w_s,
    const float* __restrict__ ln_g, const float* __restrict__ ln_b,
    const float* __restrict__ bias_w, float* __restrict__ ws)
{
    __shared__ __align__(16) float mvn[256];    // [i][b] = i*16+b
    __shared__ __align__(16) float sn[128];
    __shared__ float qs_pre[256];
    __shared__ float ks_pre[32];
    __shared__ float vs_pre[32];
    const int n = blockIdx.x, t = threadIdx.x;

    mvn[t] = mv[n * 256 + t];
    if (t < 128) sn[t] = s[n * 128 + t];
    __syncthreads();

    // q_s pre-rope: 256 outputs, one per thread
    {
        const float4* w = (const float4*)(q_w_s + t * 128);
        const float4* sv = (const float4*)sn;
        float acc = 0.f;
        #pragma unroll
        for (int c4 = 0; c4 < 32; ++c4) {
            float4 wv = w[c4], x = sv[c4];
            acc += wv.x * x.x + wv.y * x.y + wv.z * x.z + wv.w * x.w;
        }
        qs_pre[t] = acc;
    }
    // k_s (t<32), v_s (32<=t<64)
    if (t < 64) {
        const float* wb = (t < 32) ? (k_w_s + t * 128) : (v_w_s + (t - 32) * 128);
        const float4* w = (const float4*)wb;
        const float4* sv = (const float4*)sn;
        float acc = 0.f;
        #pragma unroll
        for (int c4 = 0; c4 < 32; ++c4) {
            float4 wv = w[c4], x = sv[c4];
            acc += wv.x * x.x + wv.y * x.y + wv.z * x.z + wv.w * x.w;
        }
        if (t < 32) ks_pre[t] = acc; else vs_pre[t - 32] = acc;
    }
    // q_mv inner blades: o = t>>3 (0..31), j = t&7
    {
        int o = t >> 3, j = t & 7;
        int bx = INNER_C[j], g = GRADE_C[bx];
        float acc = 0.f;
        #pragma unroll
        for (int i = 0; i < 16; ++i)
            acc += mvn[i * 16 + bx] * q_w_mv[(o * 16 + i) * 5 + g];
        int h = o >> 2, c = o & 3, d = c * 8 + j;
        ws[OFF_QFT + n * 512 + d * 8 + h] = acc;
    }
    // k_mv inner: 32 outputs
    if (t < 32) {
        int c = t >> 3, j = t & 7, bx = INNER_C[j], g = GRADE_C[bx];
        float acc = 0.f;
        #pragma unroll
        for (int i = 0; i < 16; ++i)
            acc += mvn[i * 16 + bx] * k_w_mv[(c * 16 + i) * 5 + g];
        ws[OFF_KF + n * 64 + c * 8 + j] = acc;
    }
    // v_mv full 16 blades: 64 outputs (t in [64,128))
    if (t >= 64 && t < 128) {
        int idx = t - 64, c = idx >> 4, x = idx & 15, g = GRADE_C[x];
        float acc = 0.f;
        #pragma unroll
        for (int i = 0; i < 16; ++i)
            acc += mvn[i * 16 + x] * v_w_mv[(c * 16 + i) * 5 + g];
        ws[OFF_VC + n * 96 + c * 16 + x] = acc;
    }
    __syncthreads();

    // rope(q_s): h = t>>5, dd = t&31
    {
        int h = t >> 5, dd = t & 31, i = dd >> 1;
        float freq = exp2f(-0.75f * (float)i);
        float ang = (float)n * freq;
        float cv = cosf(ang), sv = sinf(ang);
        float x1 = qs_pre[h * 32 + 2 * i], x2 = qs_pre[h * 32 + 2 * i + 1];
        float val = ((dd & 1) == 0) ? (x1 * cv - x2 * sv) : (x1 * sv + x2 * cv);
        ws[OFF_QFT + n * 512 + (32 + dd) * 8 + h] = val;
    }
    // rope(k_s)
    if (t < 32) {
        int dd = t, i = dd >> 1;
        float freq = exp2f(-0.75f * (float)i);
        float ang = (float)n * freq;
        float cv = cosf(ang), sv = sinf(ang);
        float x1 = ks_pre[2 * i], x2 = ks_pre[2 * i + 1];
        float val = ((dd & 1) == 0) ? (x1 * cv - x2 * sv) : (x1 * sv + x2 * cv);
        ws[OFF_KF + n * 64 + 32 + dd] = val;
    }
    if (t >= 32 && t < 64) ws[OFF_VC + n * 96 + 64 + (t - 32)] = vs_pre[t - 32];

    // folded LN constants (block 0 only)
    if (n == 0) {
        if (t < 128) {
            float g = ln_g[t];
            #pragma unroll
            for (int h = 0; h < 8; ++h)
                ws[OFF_GW + t * 8 + h] = g * bias_w[t * 8 + h];
        }
        if (t >= 128 && t < 136) {
            int h = t - 128;
            float gh = 0.f, ch = 0.f;
            for (int c = 0; c < 128; ++c) {
                gh += ln_g[c] * bias_w[c * 8 + h];
                ch += ln_b[c] * bias_w[c * 8 + h];
            }
            ws[OFF_GH + h] = gh;
            ws[OFF_GH + 8 + h] = ch;
        }
    }
}

// ---------------- kernel A: fused LN-bias + logits -> s (bf16) ----------------
__global__ __launch_bounds__(256) void kbias(
    const float* __restrict__ z, float* __restrict__ ws)
{
    __shared__ __align__(16) float qft[512];   // qfT[q]: [d(64)][h(8)]
    __shared__ __align__(16) float gw[1024];   // [c(128)][h(8)]
    __shared__ float GhCh[16];
    const int bid = blockIdx.x;
    const int q = bid >> 3, kt = bid & 7;
    const int t = threadIdx.x;

    qft[t]       = ws[OFF_QFT + q * 512 + t];
    qft[256 + t] = ws[OFF_QFT + q * 512 + 256 + t];
    #pragma unroll
    for (int j = 0; j < 4; ++j) gw[t + j * 256] = ws[OFF_GW + t + j * 256];
    if (t < 16) GhCh[t] = ws[OFF_GH + t];
    __syncthreads();

    const int r = t >> 1, half = t & 1;
    const int k = kt * 128 + r;

    const float4* zp = (const float4*)(z + ((size_t)q * 1024 + k) * 128 + half * 64);
    float4 zz[16];
    #pragma unroll
    for (int i = 0; i < 16; ++i) zz[i] = zp[i];
    const float4* kfp = (const float4*)(ws + OFF_KF + k * 64 + half * 32);
    float4 kk[8];
    #pragma unroll
    for (int i = 0; i < 8; ++i) kk[i] = kfp[i];

    const float4* gwv = (const float4*)gw;
    const float4* qfv = (const float4*)qft;

    float sum = 0.f, sumsq = 0.f;
    float dg[8] = {0,0,0,0,0,0,0,0};
    float dq[8] = {0,0,0,0,0,0,0,0};

    #pragma unroll
    for (int i = 0; i < 16; ++i) {
        float zc4[4] = {zz[i].x, zz[i].y, zz[i].z, zz[i].w};
        #pragma unroll
        for (int j = 0; j < 4; ++j) {
            int c = half * 64 + i * 4 + j;
            float zc = zc4[j];
            sum += zc; sumsq += zc * zc;
            float4 g0 = gwv[c * 2], g1 = gwv[c * 2 + 1];
            dg[0] += zc * g0.x; dg[1] += zc * g0.y; dg[2] += zc * g0.z; dg[3] += zc * g0.w;
            dg[4] += zc * g1.x; dg[5] += zc * g1.y; dg[6] += zc * g1.z; dg[7] += zc * g1.w;
        }
    }
    #pragma unroll
    for (int i = 0; i < 8; ++i) {
        float kc4[4] = {kk[i].x, kk[i].y, kk[i].z, kk[i].w};
        #pragma unroll
        for (int j = 0; j < 4; ++j) {
            int d = half * 32 + i * 4 + j;
            float kc = kc4[j];
            float4 q0 = qfv[d * 2], q1 = qfv[d * 2 + 1];
            dq[0] += kc * q0.x; dq[1] += kc * q0.y; dq[2] += kc * q0.z; dq[3] += kc * q0.w;
            dq[4] += kc * q1.x; dq[5] += kc * q1.y; dq[6] += kc * q1.z; dq[7] += kc * q1.w;
        }
    }
    // combine lane pair
    sum   += __shfl_xor(sum, 1);
    sumsq += __shfl_xor(sumsq, 1);
    #pragma unroll
    for (int h = 0; h < 8; ++h) {
        dg[h] += __shfl_xor(dg[h], 1);
        dq[h] += __shfl_xor(dq[h], 1);
    }
    if (half == 0) {
        float mean = sum * (1.f / 128.f);
        float var  = sumsq * (1.f / 128.f) - mean * mean;
        float rs   = rsqrtf(var + 1e-5f);
        unsigned short u[8];
        #pragma unroll
        for (int h = 0; h < 8; ++h) {
            float bias = rs * (dg[h] - mean * GhCh[h]) + GhCh[8 + h];
            float sval = dq[h] * 0.125f + bias;
            u[h] = f2bf(sval);
        }
        uint4 pk;
        pk.x = (unsigned)u[0] | ((unsigned)u[1] << 16);
        pk.y = (unsigned)u[2] | ((unsigned)u[3] << 16);
        pk.z = (unsigned)u[4] | ((unsigned)u[5] << 16);
        pk.w = (unsigned)u[6] | ((unsigned)u[7] << 16);
        unsigned short* sb = (unsigned short*)((char*)ws + SB_BYTE);
        *(uint4*)(sb + ((size_t)q * 1024 + k) * 8) = pk;
    }
}

// ---------------- kernel B: softmax + PV + output projections ----------------
__global__ __launch_bounds__(256) void kattn(
    const float* __restrict__ ws,
    const float* __restrict__ out_w_mv, const float* __restrict__ out_w_s,
    float* __restrict__ d_out)
{
    __shared__ __align__(16) float Sl[8 * 1024];  // [h][k]
    __shared__ float inv_l[8];
    __shared__ float o_sh[8 * 96];
    const int q = blockIdx.x, t = threadIdx.x;

    const unsigned short* sb =
        (const unsigned short*)((const char*)ws + SB_BYTE) + (size_t)q * 8192;
    #pragma unroll
    for (int it = 0; it < 4; ++it) {
        int k = t + it * 256;
        uint4 rv = *(const uint4*)(sb + (size_t)k * 8);
        Sl[0 * 1024 + k] = bf2f(rv.x & 0xffffu);
        Sl[1 * 1024 + k] = bf2f(rv.x >> 16);
        Sl[2 * 1024 + k] = bf2f(rv.y & 0xffffu);
        Sl[3 * 1024 + k] = bf2f(rv.y >> 16);
        Sl[4 * 1024 + k] = bf2f(rv.z & 0xffffu);
        Sl[5 * 1024 + k] = bf2f(rv.z >> 16);
        Sl[6 * 1024 + k] = bf2f(rv.w & 0xffffu);
        Sl[7 * 1024 + k] = bf2f(rv.w >> 16);
    }
    __syncthreads();

    const int h = t >> 5, e = t & 31;
    // per-head max (32 lanes per head)
    float m = -1e30f;
    #pragma unroll 8
    for (int j = 0; j < 32; ++j) m = fmaxf(m, Sl[h * 1024 + e + j * 32]);
    #pragma unroll
    for (int d = 16; d >= 1; d >>= 1) m = fmaxf(m, __shfl_xor(m, d));
    // exp + sum (write p back unnormalized)
    float lsum = 0.f;
    #pragma unroll 8
    for (int j = 0; j < 32; ++j) {
        int kk = e + j * 32;
        float p = __expf(Sl[h * 1024 + kk] - m);
        Sl[h * 1024 + kk] = p;
        lsum += p;
    }
    #pragma unroll
    for (int d = 16; d >= 1; d >>= 1) lsum += __shfl_xor(lsum, d);
    if (e == 0) inv_l[h] = 1.f / lsum;
    __syncthreads();

    // PV: thread (h,e) accumulates elems e, e+32, e+64 over all k
    const float* Vc = ws + OFF_VC;
    const float* Ph = &Sl[h * 1024];
    float a0 = 0.f, a1 = 0.f, a2 = 0.f;
    for (int k0 = 0; k0 < 1024; k0 += 4) {
        float4 p4 = *(const float4*)(Ph + k0);
        float pv[4] = {p4.x, p4.y, p4.z, p4.w};
        #pragma unroll
        for (int j = 0; j < 4; ++j) {
            const float* vr = Vc + (size_t)(k0 + j) * 96 + e;
            a0 += pv[j] * vr[0];
            a1 += pv[j] * vr[32];
            a2 += pv[j] * vr[64];
        }
    }
    float il = inv_l[h];
    o_sh[h * 96 + e]      = a0 * il;
    o_sh[h * 96 + e + 32] = a1 * il;
    o_sh[h * 96 + e + 64] = a2 * il;
    __syncthreads();

    // out_mv: 256 outputs: o2 = t>>4, b = t&15
    {
        int o2 = t >> 4, b = t & 15, g = GRADE_C[b];
        float acc = 0.f;
        #pragma unroll
        for (int i = 0; i < 32; ++i)
            acc += o_sh[(i >> 2) * 96 + (i & 3) * 16 + b] *
                   out_w_mv[(o2 * 32 + i) * 5 + g];
        d_out[(q * 16 + o2) * 16 + b] = acc;
    }
    // out_s: 128 outputs
    if (t < 128) {
        const float* w = out_w_s + t * 256;
        float acc = 0.f;
        #pragma unroll 4
        for (int c = 0; c < 256; ++c)
            acc += o_sh[(c >> 5) * 96 + 64 + (c & 31)] * w[c];
        d_out[262144 + q * 128 + t] = acc;
    }
}

// ---------------- launch ----------------
extern "C" void kernel_launch(void* const* d_in, const int* in_sizes, int n_in,
                              void* d_out, int out_size, void* d_ws, size_t ws_size,
                              hipStream_t stream) {
    (void)in_sizes; (void)n_in; (void)out_size; (void)ws_size;
    const float* mv       = (const float*)d_in[0];
    const float* s        = (const float*)d_in[1];
    const float* z        = (const float*)d_in[2];
    const float* q_w_mv   = (const float*)d_in[3];
    const float* q_w_s    = (const float*)d_in[4];
    const float* k_w_mv   = (const float*)d_in[5];
    const float* k_w_s    = (const float*)d_in[6];
    const float* v_w_mv   = (const float*)d_in[7];
    const float* v_w_s    = (const float*)d_in[8];
    const float* out_w_mv = (const float*)d_in[9];
    const float* out_w_s  = (const float*)d_in[10];
    const float* ln_g     = (const float*)d_in[11];
    const float* ln_b     = (const float*)d_in[12];
    const float* bias_w   = (const float*)d_in[13];
    float* ws  = (float*)d_ws;
    float* out = (float*)d_out;

    kproj<<<1024, 256, 0, stream>>>(mv, s, q_w_mv, q_w_s, k_w_mv, k_w_s,
                                    v_w_mv, v_w_s, ln_g, ln_b, bias_w, ws);
    kbias<<<8192, 256, 0, stream>>>(z, ws);
    kattn<<<1024, 256, 0, stream>>>(ws, out_w_mv, out_w_s, out);
}